// Round 1
// baseline (998.032 us; speedup 1.0000x reference)
//
#include <hip/hip_runtime.h>
#include <hip/hip_bf16.h>

// Problem dims (fixed by setup_inputs)
#define BB 4
#define LL 4096
#define HH 8
#define DD 64
#define MM 256
#define XDIM 72           // D + S/H = 64 + 8
#define CE 65             // Dv + 1
#define NSPLIT 16
#define KC (LL / NSPLIT)  // 256 keys per block

#define NORMALIZER 0.35355339059327373f  // 64^-0.25
#define INV_SQRT_M 0.0625f               // 1/sqrt(256)
#define EPSV 1e-6f

// ---------------------------------------------------------------------------
// Kernel 1: fourier embeddings for qs_s (with per-head a folded in) and ks_s.
// qs_sp/ks_sp layout: [B*L][64]; element j<32 = sin(2pi*s*W[j]), j>=32 = cos.
// Head h owns elements [h*8, h*8+8).
// ---------------------------------------------------------------------------
__global__ __launch_bounds__(256) void embed_k(
    const float* __restrict__ qs_s, const float* __restrict__ ks_s,
    const float* __restrict__ W, const float* __restrict__ a,
    float* __restrict__ qs_sp, float* __restrict__ ks_sp) {
  int idx = blockIdx.x * 256 + threadIdx.x;
  if (idx >= BB * LL) return;
  const float TWO_PI = 6.28318530717958647692f;
  float sq = qs_s[idx] * TWO_PI;
  float sk = ks_s[idx] * TWO_PI;
  float* qd = qs_sp + (size_t)idx * 64;
  float* kd = ks_sp + (size_t)idx * 64;
#pragma unroll
  for (int j = 0; j < 32; ++j) {
    float w = W[j];
    float aj_s = a[j >> 3];         // head of sin element j
    float aj_c = a[(32 + j) >> 3];  // head of cos element 32+j
    float sjq = sinf(sq * w), cjq = cosf(sq * w);
    float sjk = sinf(sk * w), cjk = cosf(sk * w);
    qd[j] = aj_s * sjq;
    qd[32 + j] = aj_c * cjq;
    kd[j] = sjk;
    kd[32 + j] = cjk;
  }
}

// ---------------------------------------------------------------------------
// Kernel 2: hq/hk = 0.5*||x||^2 per (b,l,h), x = [qs*norm, s'(8)]
// ---------------------------------------------------------------------------
__global__ __launch_bounds__(256) void hsum_k(
    const float* __restrict__ qs, const float* __restrict__ ks,
    const float* __restrict__ qs_sp, const float* __restrict__ ks_sp,
    float* __restrict__ hq, float* __restrict__ hk) {
  int t = blockIdx.x * 256 + threadIdx.x;  // (b*L + l)*H + h
  if (t >= BB * LL * HH) return;
  int bl = t / HH, h = t % HH;
  const float* xq = qs + (size_t)t * 64;
  const float* xk = ks + (size_t)t * 64;
  float sq = 0.f, sk = 0.f;
#pragma unroll 8
  for (int d = 0; d < 64; ++d) {
    float vq = xq[d] * NORMALIZER;
    float vk = xk[d] * NORMALIZER;
    sq += vq * vq;
    sk += vk * vk;
  }
  const float* eq = qs_sp + (size_t)bl * 64 + h * 8;
  const float* ek = ks_sp + (size_t)bl * 64 + h * 8;
#pragma unroll
  for (int i = 0; i < 8; ++i) {
    sq += eq[i] * eq[i];
    sk += ek[i] * ek[i];
  }
  hq[t] = 0.5f * sq;
  hk[t] = 0.5f * sk;
}

// ---------------------------------------------------------------------------
// Kernel 3: buf1[b,h,m,e] += sum_k phi_k[m] * c[k,e]   (split-K, atomics)
// Thread m owns feature m: proj row (normalizer folded into first 64) in
// VGPRs; per-key x/c/h reads are wave-uniform -> expect s_load + SGPR-operand
// v_fma. No LDS, no barriers.
// ---------------------------------------------------------------------------
__global__ __launch_bounds__(256, 2) void buf1_k(
    const float* __restrict__ ks, const float* __restrict__ vs,
    const float* __restrict__ proj, const float* __restrict__ ks_sp,
    const float* __restrict__ hk, float* __restrict__ buf1) {
  int bh = blockIdx.x;          // 0..31
  int split = blockIdx.y;       // 0..NSPLIT-1
  int b = bh / HH, h = bh % HH;
  int m = threadIdx.x;

  float pr[XDIM];
#pragma unroll
  for (int d = 0; d < 64; ++d) pr[d] = proj[(size_t)m * XDIM + d] * NORMALIZER;
#pragma unroll
  for (int d = 64; d < XDIM; ++d) pr[d] = proj[(size_t)m * XDIM + d];

  float acc[CE];
#pragma unroll
  for (int e = 0; e < CE; ++e) acc[e] = 0.f;

  int k0 = split * KC;
  for (int k = k0; k < k0 + KC; ++k) {
    size_t t = ((size_t)b * LL + k) * HH + h;
    const float* xk = ks + t * 64;                       // uniform
    const float* sp = ks_sp + ((size_t)b * LL + k) * 64 + h * 8;  // uniform
    float s = 0.f;
#pragma unroll
    for (int d = 0; d < 64; ++d) s += pr[d] * xk[d];
#pragma unroll
    for (int i = 0; i < 8; ++i) s += pr[64 + i] * sp[i];
    float p = __expf(s - hk[t]) * INV_SQRT_M;
    const float* cv = vs + t * 64;                       // uniform
#pragma unroll
    for (int e = 0; e < 64; ++e) acc[e] += p * cv[e];
    acc[64] += p;
  }

  float* dst = buf1 + ((size_t)bh * MM + m) * CE;
#pragma unroll
  for (int e = 0; e < CE; ++e) atomicAdd(dst + e, acc[e]);
}

// ---------------------------------------------------------------------------
// Kernel 4: out[b,q,h,:] = (sum_m qphi[m] * buf1[m,:64]) / max(den, eps)
// Thread per query; proj/buf1 reads wave-uniform -> scalar loads.
// ---------------------------------------------------------------------------
__global__ __launch_bounds__(256, 2) void out_k(
    const float* __restrict__ qs, const float* __restrict__ proj,
    const float* __restrict__ qs_sp, const float* __restrict__ hq,
    const float* __restrict__ buf1, float* __restrict__ out) {
  int bh = blockIdx.y;  // 0..31
  int q = blockIdx.x * 256 + threadIdx.x;
  int b = bh / HH, h = bh % HH;
  size_t t = ((size_t)b * LL + q) * HH + h;

  float x[XDIM];
  const float* xq = qs + t * 64;
#pragma unroll
  for (int d = 0; d < 64; ++d) x[d] = xq[d] * NORMALIZER;
  const float* eq = qs_sp + ((size_t)b * LL + q) * 64 + h * 8;
#pragma unroll
  for (int i = 0; i < 8; ++i) x[64 + i] = eq[i];
  float hqv = hq[t];

  float acc[CE];
#pragma unroll
  for (int e = 0; e < CE; ++e) acc[e] = 0.f;

  const float* bp = buf1 + (size_t)bh * MM * CE;
  for (int mm = 0; mm < MM; ++mm) {
    const float* prow = proj + (size_t)mm * XDIM;  // uniform
    float s = 0.f;
#pragma unroll
    for (int d = 0; d < XDIM; ++d) s += prow[d] * x[d];
    float p = __expf(s - hqv) * INV_SQRT_M;
    const float* brow = bp + (size_t)mm * CE;      // uniform
#pragma unroll
    for (int e = 0; e < CE; ++e) acc[e] += p * brow[e];
  }

  float den = acc[64];
  den = den < EPSV ? EPSV : den;
  float inv = 1.f / den;
  float* od = out + t * 64;
#pragma unroll
  for (int e = 0; e < 64; ++e) od[e] = acc[e] * inv;
}

// ---------------------------------------------------------------------------
extern "C" void kernel_launch(void* const* d_in, const int* in_sizes, int n_in,
                              void* d_out, int out_size, void* d_ws, size_t ws_size,
                              hipStream_t stream) {
  const float* qs    = (const float*)d_in[0];
  const float* ks    = (const float*)d_in[1];
  const float* vs    = (const float*)d_in[2];
  const float* qs_s  = (const float*)d_in[3];
  const float* ks_s  = (const float*)d_in[4];
  const float* W     = (const float*)d_in[5];
  const float* proj  = (const float*)d_in[6];
  const float* a     = (const float*)d_in[7];
  float* out = (float*)d_out;

  float* ws = (float*)d_ws;
  float* qs_sp = ws;                          // B*L*64
  float* ks_sp = qs_sp + (size_t)BB * LL * 64;
  float* hq    = ks_sp + (size_t)BB * LL * 64;  // B*L*H
  float* hk    = hq + (size_t)BB * LL * HH;
  float* buf1  = hk + (size_t)BB * LL * HH;     // B*H*M*CE

  hipMemsetAsync(buf1, 0, (size_t)BB * HH * MM * CE * sizeof(float), stream);

  embed_k<<<(BB * LL + 255) / 256, 256, 0, stream>>>(qs_s, ks_s, W, a, qs_sp, ks_sp);
  hsum_k<<<(BB * LL * HH + 255) / 256, 256, 0, stream>>>(qs, ks, qs_sp, ks_sp, hq, hk);
  buf1_k<<<dim3(BB * HH, NSPLIT), 256, 0, stream>>>(ks, vs, proj, ks_sp, hk, buf1);
  out_k<<<dim3(LL / 256, BB * HH), 256, 0, stream>>>(qs, proj, qs_sp, hq, buf1, out);
}

// Round 2
// 231.182 us; speedup vs baseline: 4.3171x; 4.3171x over previous
//
#include <hip/hip_runtime.h>
#include <hip/hip_bf16.h>
#include <math.h>

// Problem dims (fixed by setup_inputs)
#define BB 4
#define LLEN 4096
#define HH 8
#define MM 256
#define KX 96          // padded x-dim: 64 qk + 8 fourier + 24 zero
#define EE 80          // padded c-dim: 64 v + 1 ones + 15 zero
#define NORM 0.35355339059327373f   // 64^-0.25 (folded into projB cols 0..63)
#define NORM2 0.125f                // NORM^2
#define INV_SQRT_M 0.0625f
#define EPSV 1e-6f
#define TWO_PI_F 6.283185307179586f

typedef __attribute__((ext_vector_type(8))) short s16x8;   // 8 bf16 (4 VGPRs)
typedef __attribute__((ext_vector_type(4))) float f32x4;   // MFMA acc

#define MFMA16(A,B,C) __builtin_amdgcn_mfma_f32_16x16x32_bf16(A,B,C,0,0,0)

static __device__ __forceinline__ unsigned short f2bf(float f) {
  union { float f; unsigned int u; } v; v.f = f;
  unsigned int r = v.u + 0x7FFFu + ((v.u >> 16) & 1u);   // round-to-nearest-even
  return (unsigned short)(r >> 16);
}
static __device__ __forceinline__ s16x8 ldg8(const unsigned short* p) {
  return *reinterpret_cast<const s16x8*>(p);
}

// ---- workspace byte offsets (total ~115.7 MB) ----
#define OFF_PROJB 0u
#define OFF_XQ    49152u
#define OFF_XK    (OFF_XQ + 25165824u)
#define OFF_HQ    (OFF_XK + 25165824u)
#define OFF_HK    (OFF_HQ + 524288u)
#define OFF_VST   (OFF_HK + 524288u)
#define OFF_PARTS (OFF_VST + 20971520u)
#define OFF_B1T   (OFF_PARTS + 41943040u)

// ---------------------------------------------------------------------------
// projB[m][0..95] bf16: cols 0..63 = proj*NORM, 64..71 = proj, 72..95 = 0
// ---------------------------------------------------------------------------
__global__ __launch_bounds__(256) void prep_proj(const float* __restrict__ proj,
                                                 unsigned short* __restrict__ projB) {
  int m = threadIdx.x;
#pragma unroll
  for (int d = 0; d < 64; ++d) projB[m * KX + d] = f2bf(proj[m * 72 + d] * NORM);
#pragma unroll
  for (int d = 64; d < 72; ++d) projB[m * KX + d] = f2bf(proj[m * 72 + d]);
#pragma unroll
  for (int d = 72; d < 96; ++d) projB[m * KX + d] = 0;
}

// ---------------------------------------------------------------------------
// Per (token,h): Xq/Xk rows [96] bf16 (raw qk + fourier embed (+a on q) + 0s),
// hq/hk = 0.5*||x_normalized||^2 in f32.
// ---------------------------------------------------------------------------
__global__ __launch_bounds__(256) void prep_x(
    const float* __restrict__ qs, const float* __restrict__ ks,
    const float* __restrict__ qs_s, const float* __restrict__ ks_s,
    const float* __restrict__ W, const float* __restrict__ a,
    unsigned short* __restrict__ Xq, unsigned short* __restrict__ Xk,
    float* __restrict__ hq, float* __restrict__ hk) {
  int t = blockIdx.x * 256 + threadIdx.x;   // t = token*8 + h, 131072 total
  int token = t >> 3, h = t & 7;
  float sq = qs_s[token] * TWO_PI_F, sk = ks_s[token] * TWO_PI_F;
  float ah = a[h];
  float eq[8], ek[8];
#pragma unroll
  for (int j = 0; j < 8; ++j) {
    int dim = 8 * h + j;
    float w = W[dim & 31];
    float pq = sq * w, pk = sk * w;
    if (dim < 32) { eq[j] = sinf(pq); ek[j] = sinf(pk); }
    else          { eq[j] = cosf(pq); ek[j] = cosf(pk); }
  }
  const f32x4* xqv = reinterpret_cast<const f32x4*>(qs + (size_t)t * 64);
  const f32x4* xkv = reinterpret_cast<const f32x4*>(ks + (size_t)t * 64);
  unsigned short* oq = Xq + (size_t)t * KX;
  unsigned short* ok = Xk + (size_t)t * KX;
  float sumq = 0.f, sumk = 0.f;
#pragma unroll
  for (int sg = 0; sg < 16; ++sg) {
    f32x4 vq = xqv[sg], vk = xkv[sg];
#pragma unroll
    for (int i = 0; i < 4; ++i) {
      sumq += vq[i] * vq[i]; sumk += vk[i] * vk[i];
      oq[sg * 4 + i] = f2bf(vq[i]);
      ok[sg * 4 + i] = f2bf(vk[i]);
    }
  }
  float s2q = 0.f, s2k = 0.f;
#pragma unroll
  for (int j = 0; j < 8; ++j) {
    float vq = ah * eq[j], vk = ek[j];
    s2q += vq * vq; s2k += vk * vk;
    oq[64 + j] = f2bf(vq);
    ok[64 + j] = f2bf(vk);
  }
#pragma unroll
  for (int j = 72; j < 96; ++j) { oq[j] = 0; ok[j] = 0; }
  hq[t] = 0.5f * (sumq * NORM2 + s2q);
  hk[t] = 0.5f * (sumk * NORM2 + s2k);
}

// ---------------------------------------------------------------------------
// vsT[bh][e][k] bf16 for e<64 via LDS tile transpose (rows 64..79 by prep_fill)
// ---------------------------------------------------------------------------
__global__ __launch_bounds__(256) void prep_vst(const float* __restrict__ vs,
                                                unsigned short* __restrict__ vsT) {
  int kc = blockIdx.x;   // 0..63
  int bh = blockIdx.y;   // 0..31
  int b = bh >> 3, h = bh & 7;
  int t = threadIdx.x;
  __shared__ unsigned short tile[64][72];
  int k = t >> 2, seg = t & 3;
  const f32x4* src = reinterpret_cast<const f32x4*>(
      vs + (((size_t)(b * LLEN + kc * 64 + k)) * HH + h) * 64 + seg * 16);
#pragma unroll
  for (int j = 0; j < 4; ++j) {
    f32x4 v = src[j];
#pragma unroll
    for (int i = 0; i < 4; ++i) tile[k][seg * 16 + j * 4 + i] = f2bf(v[i]);
  }
  __syncthreads();
  int e = t >> 2, ksg = t & 3;
  s16x8 o0, o1;
#pragma unroll
  for (int j = 0; j < 8; ++j) o0[j] = (short)tile[ksg * 16 + j][e];
#pragma unroll
  for (int j = 0; j < 8; ++j) o1[j] = (short)tile[ksg * 16 + 8 + j][e];
  unsigned short* dst = vsT + ((size_t)bh * EE + e) * LLEN + kc * 64 + ksg * 16;
  *reinterpret_cast<s16x8*>(dst) = o0;
  *reinterpret_cast<s16x8*>(dst + 8) = o1;
}

__global__ __launch_bounds__(256) void prep_fill(unsigned short* __restrict__ vsT) {
  int t = blockIdx.x * 256 + threadIdx.x;   // 262144 threads, 8 u16 each
  int f0 = t * 8;                            // over 32*16*4096
  int bh = f0 >> 16;
  int rem = f0 & 65535;
  int er = rem >> 12;
  int k = rem & 4095;
  unsigned short val = (er == 0) ? f2bf(1.0f) : (unsigned short)0;
  s16x8 v;
#pragma unroll
  for (int i = 0; i < 8; ++i) v[i] = (short)val;
  *reinterpret_cast<s16x8*>(vsT + ((size_t)bh * EE + 64 + er) * LLEN + k) = v;
}

// ---------------------------------------------------------------------------
// F1: fused phi_k GEMM + exp + buf1 GEMM, per (bh, ksplit). No barriers:
// each wave owns disjoint 64 m-rows of P_lds.
// ---------------------------------------------------------------------------
__global__ __launch_bounds__(256, 2) void f1_k(
    const unsigned short* __restrict__ Xk, const unsigned short* __restrict__ projB,
    const unsigned short* __restrict__ vsT, const float* __restrict__ hk,
    float* __restrict__ parts) {
  int bh = blockIdx.x, split = blockIdx.y;
  int b = bh >> 3, h = bh & 7;
  int wave = threadIdx.x >> 6, l = threadIdx.x & 63;
  int l15 = l & 15, l4 = l >> 4;
  __shared__ alignas(16) unsigned short P[256][72];   // [m][key_local], 8-pad
  f32x4 acc2[4][5] = {};

  for (int chunk = 0; chunk < 4; ++chunk) {
    int k0 = split * 256 + chunk * 64;
    f32x4 acc1[4][4] = {};
#pragma unroll
    for (int ks = 0; ks < 3; ++ks) {
      s16x8 afr[4];
#pragma unroll
      for (int mt = 0; mt < 4; ++mt)
        afr[mt] = ldg8(projB + (size_t)(l15 + 16 * (4 * wave + mt)) * KX + 32 * ks + 8 * l4);
#pragma unroll
      for (int kt = 0; kt < 4; ++kt) {
        s16x8 bfr = ldg8(Xk + ((size_t)(b * LLEN + k0 + l15 + 16 * kt) * HH + h) * KX + 32 * ks + 8 * l4);
#pragma unroll
        for (int mt = 0; mt < 4; ++mt) acc1[mt][kt] = MFMA16(afr[mt], bfr, acc1[mt][kt]);
      }
    }
    // epilogue: p = exp(s - hk)*inv_sqrt_m -> P_lds (own wave's rows only)
#pragma unroll
    for (int kt = 0; kt < 4; ++kt) {
      int key = k0 + l15 + 16 * kt;
      float hkv = hk[(size_t)(b * LLEN + key) * HH + h];
#pragma unroll
      for (int mt = 0; mt < 4; ++mt) {
        int mrow = 16 * (4 * wave + mt) + 4 * l4;
#pragma unroll
        for (int r = 0; r < 4; ++r) {
          float p = __expf(acc1[mt][kt][r] - hkv) * INV_SQRT_M;
          P[mrow + r][l15 + 16 * kt] = f2bf(p);
        }
      }
    }
    // GEMM2: acc2[m][e] += P[m][k] * vsT[e][k]
#pragma unroll
    for (int ks2 = 0; ks2 < 2; ++ks2) {
      s16x8 afr2[4];
#pragma unroll
      for (int mt = 0; mt < 4; ++mt)
        afr2[mt] = *reinterpret_cast<const s16x8*>(&P[l15 + 16 * (4 * wave + mt)][32 * ks2 + 8 * l4]);
#pragma unroll
      for (int nt = 0; nt < 5; ++nt) {
        s16x8 bfr2 = ldg8(vsT + ((size_t)bh * EE + l15 + 16 * nt) * LLEN + k0 + 32 * ks2 + 8 * l4);
#pragma unroll
        for (int mt = 0; mt < 4; ++mt) acc2[mt][nt] = MFMA16(afr2[mt], bfr2, acc2[mt][nt]);
      }
    }
  }
  // store per-split partials
#pragma unroll
  for (int mt = 0; mt < 4; ++mt)
#pragma unroll
    for (int nt = 0; nt < 5; ++nt)
#pragma unroll
      for (int r = 0; r < 4; ++r) {
        int m = 16 * (4 * wave + mt) + 4 * l4 + r;
        int e = l15 + 16 * nt;
        parts[(((size_t)split * 32 + bh) * MM + m) * EE + e] = acc2[mt][nt][r];
      }
}

// ---------------------------------------------------------------------------
// reduce 16 splits -> buf1T bf16 [bh][80 e][256 m]
// ---------------------------------------------------------------------------
__global__ __launch_bounds__(256) void reduce_t(const float* __restrict__ parts,
                                                unsigned short* __restrict__ b1T) {
  int bh = blockIdx.x;   // 32
  int mc = blockIdx.y;   // 4 (64 m each)
  __shared__ float s[64 * 80];
  size_t base = ((size_t)bh * MM + mc * 64) * EE;
  for (int o = threadIdx.x; o < 64 * 80; o += 256) {
    float sum = 0.f;
#pragma unroll
    for (int sp = 0; sp < 16; ++sp)
      sum += parts[(size_t)sp * 32 * MM * EE + base + o];
    s[o] = sum;
  }
  __syncthreads();
  for (int o = threadIdx.x; o < 64 * 80; o += 256) {
    int e = o >> 6, ml = o & 63;
    b1T[((size_t)bh * EE + e) * MM + mc * 64 + ml] = f2bf(s[ml * 80 + e]);
  }
}

// ---------------------------------------------------------------------------
// F2: fused phi_q GEMM + exp + output GEMM + den-normalize, per (bh, 64 q).
// ---------------------------------------------------------------------------
__global__ __launch_bounds__(256, 3) void f2_k(
    const unsigned short* __restrict__ Xq, const unsigned short* __restrict__ projB,
    const unsigned short* __restrict__ b1T, const float* __restrict__ hq,
    float* __restrict__ out) {
  int bh = blockIdx.x, qc = blockIdx.y;
  int b = bh >> 3, h = bh & 7;
  int wave = threadIdx.x >> 6, l = threadIdx.x & 63;
  int l15 = l & 15, l4 = l >> 4;
  int q0 = qc * 64;
  __shared__ alignas(16) unsigned short P[64][264];   // [q_local][m], 8-pad
  f32x4 acc1[16] = {};
#pragma unroll
  for (int ks = 0; ks < 3; ++ks) {
    s16x8 afr = ldg8(Xq + ((size_t)(b * LLEN + q0 + 16 * wave + l15) * HH + h) * KX + 32 * ks + 8 * l4);
#pragma unroll
    for (int nt = 0; nt < 16; ++nt) {
      s16x8 bfr = ldg8(projB + (size_t)(l15 + 16 * nt) * KX + 32 * ks + 8 * l4);
      acc1[nt] = MFMA16(afr, bfr, acc1[nt]);
    }
  }
  float hqv[4];
#pragma unroll
  for (int r = 0; r < 4; ++r)
    hqv[r] = hq[(size_t)(b * LLEN + q0 + 16 * wave + 4 * l4 + r) * HH + h];
#pragma unroll
  for (int nt = 0; nt < 16; ++nt)
#pragma unroll
    for (int r = 0; r < 4; ++r) {
      float p = __expf(acc1[nt][r] - hqv[r]) * INV_SQRT_M;
      P[16 * wave + 4 * l4 + r][l15 + 16 * nt] = f2bf(p);
    }
  // GEMM3: out[q][e] = sum_m P[q][m] * b1T[e][m]   (reads own wave's rows)
  f32x4 acc3[5] = {};
#pragma unroll
  for (int ks3 = 0; ks3 < 8; ++ks3) {
    s16x8 afr3 = *reinterpret_cast<const s16x8*>(&P[l15 + 16 * wave][32 * ks3 + 8 * l4]);
#pragma unroll
    for (int nt = 0; nt < 5; ++nt) {
      s16x8 bfr3 = ldg8(b1T + ((size_t)bh * EE + l15 + 16 * nt) * MM + 32 * ks3 + 8 * l4);
      acc3[nt] = MFMA16(afr3, bfr3, acc3[nt]);
    }
  }
  float inv[4];
#pragma unroll
  for (int r = 0; r < 4; ++r) {
    float den = __shfl(acc3[4][r], l & 48, 64);   // e=64 column lives in lanes l15==0
    den = den < EPSV ? EPSV : den;
    inv[r] = 1.0f / den;
  }
#pragma unroll
  for (int nt = 0; nt < 4; ++nt)
#pragma unroll
    for (int r = 0; r < 4; ++r)
      out[((size_t)(b * LLEN + q0 + 16 * wave + 4 * l4 + r) * HH + h) * 64 + l15 + 16 * nt] =
          acc3[nt][r] * inv[r];
}

// ---------------------------------------------------------------------------
extern "C" void kernel_launch(void* const* d_in, const int* in_sizes, int n_in,
                              void* d_out, int out_size, void* d_ws, size_t ws_size,
                              hipStream_t stream) {
  const float* qs   = (const float*)d_in[0];
  const float* ks   = (const float*)d_in[1];
  const float* vs   = (const float*)d_in[2];
  const float* qs_s = (const float*)d_in[3];
  const float* ks_s = (const float*)d_in[4];
  const float* W    = (const float*)d_in[5];
  const float* proj = (const float*)d_in[6];
  const float* a    = (const float*)d_in[7];
  float* out = (float*)d_out;

  char* ws = (char*)d_ws;
  unsigned short* projB = (unsigned short*)(ws + OFF_PROJB);
  unsigned short* Xq    = (unsigned short*)(ws + OFF_XQ);
  unsigned short* Xk    = (unsigned short*)(ws + OFF_XK);
  float*          hq    = (float*)(ws + OFF_HQ);
  float*          hk    = (float*)(ws + OFF_HK);
  unsigned short* vsT   = (unsigned short*)(ws + OFF_VST);
  float*          parts = (float*)(ws + OFF_PARTS);
  unsigned short* b1T   = (unsigned short*)(ws + OFF_B1T);

  prep_proj<<<1, 256, 0, stream>>>(proj, projB);
  prep_x<<<512, 256, 0, stream>>>(qs, ks, qs_s, ks_s, W, a, Xq, Xk, hq, hk);
  prep_vst<<<dim3(64, 32), 256, 0, stream>>>(vs, vsT);
  prep_fill<<<1024, 256, 0, stream>>>(vsT);
  f1_k<<<dim3(32, 16), 256, 0, stream>>>(Xk, projB, vsT, hk, parts);
  reduce_t<<<dim3(32, 4), 256, 0, stream>>>(parts, b1T);
  f2_k<<<dim3(32, 64), 256, 0, stream>>>(Xq, projB, b1T, hq, out);
}

// Round 3
// 187.153 us; speedup vs baseline: 5.3327x; 1.2353x over previous
//
#include <hip/hip_runtime.h>
#include <hip/hip_bf16.h>
#include <math.h>

// Problem dims (fixed by setup_inputs)
#define BB 4
#define LLEN 4096
#define HH 8
#define MM 256
#define KX 96          // padded x-dim: 64 qk + 8 fourier + 24 zero
#define EE 80          // padded c-dim: 64 v + 1 ones + 15 zero
#define NTOK 16384     // BB*LLEN
#define NORM 0.35355339059327373f   // 64^-0.25 (folded into projB cols 0..63)
#define NORM2 0.125f                // NORM^2
#define LN16 2.7725887222397811f    // ln(sqrt(256)) folded into h => exp includes 1/sqrt(m)
#define EPSV 1e-6f
#define TWO_PI_F 6.283185307179586f
#define NSPLIT 16

typedef __attribute__((ext_vector_type(8))) short s16x8;   // 8 bf16 (4 VGPRs)
typedef __attribute__((ext_vector_type(4))) short s16x4;   // 4 bf16
typedef __attribute__((ext_vector_type(4))) float f32x4;   // MFMA acc

#define MFMA16(A,B,C) __builtin_amdgcn_mfma_f32_16x16x32_bf16(A,B,C,0,0,0)

static __device__ __forceinline__ unsigned short f2bf(float f) {
  union { float f; unsigned int u; } v; v.f = f;
  unsigned int r = v.u + 0x7FFFu + ((v.u >> 16) & 1u);   // round-to-nearest-even
  return (unsigned short)(r >> 16);
}

// ---- workspace byte offsets (total ~116 MB) ----
#define OFF_PROJB 0u
#define OFF_XQ    49152u
#define OFF_XK    (OFF_XQ + 25165824u)
#define OFF_HQ    (OFF_XK + 25165824u)
#define OFF_HK    (OFF_HQ + 524288u)
#define OFF_VST   (OFF_HK + 524288u)
#define OFF_PARTS (OFF_VST + 20971520u)
#define OFF_B1T   (OFF_PARTS + 41943040u)

// ---------------------------------------------------------------------------
// projB[m][0..95] bf16: cols 0..63 = proj*NORM, 64..71 = proj, 72..95 = 0
// ---------------------------------------------------------------------------
__global__ __launch_bounds__(256) void prep_proj(const float* __restrict__ proj,
                                                 unsigned short* __restrict__ projB) {
  int m = threadIdx.x;
#pragma unroll
  for (int d = 0; d < 64; ++d) projB[m * KX + d] = f2bf(proj[m * 72 + d] * NORM);
#pragma unroll
  for (int d = 64; d < 72; ++d) projB[m * KX + d] = f2bf(proj[m * 72 + d]);
#pragma unroll
  for (int d = 72; d < 96; ++d) projB[m * KX + d] = 0;
}

// ---------------------------------------------------------------------------
// Per (token,h): Xq/Xk rows [96] bf16 (vectorized stores), and
// hqp/hkp[h][token] = 0.5*||x||^2 + ln(16)  (f32, [h][tok] layout).
// ---------------------------------------------------------------------------
__global__ __launch_bounds__(256) void prep_x(
    const float* __restrict__ qs, const float* __restrict__ ks,
    const float* __restrict__ qs_s, const float* __restrict__ ks_s,
    const float* __restrict__ W, const float* __restrict__ a,
    unsigned short* __restrict__ Xq, unsigned short* __restrict__ Xk,
    float* __restrict__ hqp, float* __restrict__ hkp) {
  int t = blockIdx.x * 256 + threadIdx.x;   // t = token*8 + h
  int token = t >> 3, h = t & 7;
  float sq = qs_s[token] * TWO_PI_F, sk = ks_s[token] * TWO_PI_F;
  float ah = a[h];
  unsigned short* oq = Xq + (size_t)t * KX;
  unsigned short* ok = Xk + (size_t)t * KX;
  const f32x4* xqv = reinterpret_cast<const f32x4*>(qs + (size_t)t * 64);
  const f32x4* xkv = reinterpret_cast<const f32x4*>(ks + (size_t)t * 64);
  float sumq = 0.f, sumk = 0.f;
#pragma unroll
  for (int sg = 0; sg < 8; ++sg) {
    f32x4 q0 = xqv[2 * sg], q1 = xqv[2 * sg + 1];
    f32x4 k0 = xkv[2 * sg], k1 = xkv[2 * sg + 1];
    s16x8 vq, vk;
#pragma unroll
    for (int i = 0; i < 4; ++i) {
      sumq += q0[i] * q0[i] + q1[i] * q1[i];
      sumk += k0[i] * k0[i] + k1[i] * k1[i];
      vq[i] = (short)f2bf(q0[i]); vq[4 + i] = (short)f2bf(q1[i]);
      vk[i] = (short)f2bf(k0[i]); vk[4 + i] = (short)f2bf(k1[i]);
    }
    *reinterpret_cast<s16x8*>(oq + 8 * sg) = vq;
    *reinterpret_cast<s16x8*>(ok + 8 * sg) = vk;
  }
  float s2q = 0.f, s2k = 0.f;
  s16x8 eq8, ek8;
#pragma unroll
  for (int j = 0; j < 8; ++j) {
    int dim = 8 * h + j;
    float wv = W[dim & 31];
    float pq = sq * wv, pk = sk * wv;
    float vq_, vk_;
    if (dim < 32) { vq_ = ah * sinf(pq); vk_ = sinf(pk); }
    else          { vq_ = ah * cosf(pq); vk_ = cosf(pk); }
    s2q += vq_ * vq_; s2k += vk_ * vk_;
    eq8[j] = (short)f2bf(vq_); ek8[j] = (short)f2bf(vk_);
  }
  *reinterpret_cast<s16x8*>(oq + 64) = eq8;
  *reinterpret_cast<s16x8*>(ok + 64) = ek8;
  s16x8 z = {};
  *reinterpret_cast<s16x8*>(oq + 72) = z;
  *reinterpret_cast<s16x8*>(oq + 80) = z;
  *reinterpret_cast<s16x8*>(oq + 88) = z;
  *reinterpret_cast<s16x8*>(ok + 72) = z;
  *reinterpret_cast<s16x8*>(ok + 80) = z;
  *reinterpret_cast<s16x8*>(ok + 88) = z;
  hqp[h * NTOK + token] = 0.5f * (sumq * NORM2 + s2q) + LN16;
  hkp[h * NTOK + token] = 0.5f * (sumk * NORM2 + s2k) + LN16;
}

// ---------------------------------------------------------------------------
// vsT[bh][e][k] bf16 for e<64 via LDS tile transpose (rows 64..79 by prep_fill)
// ---------------------------------------------------------------------------
__global__ __launch_bounds__(256) void prep_vst(const float* __restrict__ vs,
                                                unsigned short* __restrict__ vsT) {
  int kc = blockIdx.x;   // 0..63
  int bh = blockIdx.y;   // 0..31
  int b = bh >> 3, h = bh & 7;
  int t = threadIdx.x;
  __shared__ unsigned short tile[64][72];
  int k = t >> 2, seg = t & 3;
  const f32x4* src = reinterpret_cast<const f32x4*>(
      vs + (((size_t)(b * LLEN + kc * 64 + k)) * HH + h) * 64 + seg * 16);
#pragma unroll
  for (int j = 0; j < 4; ++j) {
    f32x4 v = src[j];
#pragma unroll
    for (int i = 0; i < 4; ++i) tile[k][seg * 16 + j * 4 + i] = f2bf(v[i]);
  }
  __syncthreads();
  int e = t >> 2, ksg = t & 3;
  s16x8 o0, o1;
#pragma unroll
  for (int j = 0; j < 8; ++j) o0[j] = (short)tile[ksg * 16 + j][e];
#pragma unroll
  for (int j = 0; j < 8; ++j) o1[j] = (short)tile[ksg * 16 + 8 + j][e];
  unsigned short* dst = vsT + ((size_t)bh * EE + e) * LLEN + kc * 64 + ksg * 16;
  *reinterpret_cast<s16x8*>(dst) = o0;
  *reinterpret_cast<s16x8*>(dst + 8) = o1;
}

__global__ __launch_bounds__(256) void prep_fill(unsigned short* __restrict__ vsT) {
  int t = blockIdx.x * 256 + threadIdx.x;
  int f0 = t * 8;
  int bh = f0 >> 16;
  int rem = f0 & 65535;
  int er = rem >> 12;
  int k = rem & 4095;
  unsigned short val = (er == 0) ? f2bf(1.0f) : (unsigned short)0;
  s16x8 v;
#pragma unroll
  for (int i = 0; i < 8; ++i) v[i] = (short)val;
  *reinterpret_cast<s16x8*>(vsT + ((size_t)bh * EE + 64 + er) * LLEN + k) = v;
}

// ---------------------------------------------------------------------------
// F1: fused phi_k GEMM + exp + buf1 GEMM, all in registers (no LDS).
// GEMM1: mfma(A=Xk[key], B=projB[m]) -> lane holds P[key=16kt+4l4+r][m=l15+16nt]
// k-perm for GEMM2 (contract over key): position (l4,j) <-> key_local =
// 16(j>>2)+4l4+(j&3); A-frag = bf16(exp(acc1)) in order, B-frag (vsT) = two
// 8B loads at key 4l4 and 16+4l4.
// ---------------------------------------------------------------------------
__global__ __launch_bounds__(256, 2) void f1_k(
    const unsigned short* __restrict__ Xk, const unsigned short* __restrict__ projB,
    const unsigned short* __restrict__ vsT, const float* __restrict__ hkp,
    float* __restrict__ parts) {
  int bh = blockIdx.x, split = blockIdx.y;
  int b = bh >> 3, h = bh & 7;
  int w = threadIdx.x >> 6, l = threadIdx.x & 63;
  int l15 = l & 15, l4 = l >> 4;

  s16x8 pb[4][3];   // wave's 4 m-tiles (m = l15 + 16*(4w+nt))
#pragma unroll
  for (int nt = 0; nt < 4; ++nt)
#pragma unroll
    for (int ks = 0; ks < 3; ++ks)
      pb[nt][ks] = *reinterpret_cast<const s16x8*>(
          projB + (size_t)(l15 + 16 * (4 * w + nt)) * KX + 32 * ks + 8 * l4);

  f32x4 acc2[4][5] = {};
  const float* hkb = hkp + h * NTOK + b * LLEN;

  for (int it = 0; it < 8; ++it) {
    int k0 = split * 256 + it * 32;
    f32x4 acc1[2][4] = {};
#pragma unroll
    for (int ks = 0; ks < 3; ++ks) {
      s16x8 ak0 = *reinterpret_cast<const s16x8*>(
          Xk + ((size_t)(b * LLEN + k0 + l15) * HH + h) * KX + 32 * ks + 8 * l4);
      s16x8 ak1 = *reinterpret_cast<const s16x8*>(
          Xk + ((size_t)(b * LLEN + k0 + 16 + l15) * HH + h) * KX + 32 * ks + 8 * l4);
#pragma unroll
      for (int nt = 0; nt < 4; ++nt) {
        acc1[0][nt] = MFMA16(ak0, pb[nt][ks], acc1[0][nt]);
        acc1[1][nt] = MFMA16(ak1, pb[nt][ks], acc1[1][nt]);
      }
    }
    f32x4 hk0 = *reinterpret_cast<const f32x4*>(hkb + k0 + 4 * l4);
    f32x4 hk1 = *reinterpret_cast<const f32x4*>(hkb + k0 + 16 + 4 * l4);
    s16x8 pa[4];
#pragma unroll
    for (int nt = 0; nt < 4; ++nt)
#pragma unroll
      for (int r = 0; r < 4; ++r) {
        pa[nt][r]     = (short)f2bf(__expf(acc1[0][nt][r] - hk0[r]));
        pa[nt][4 + r] = (short)f2bf(__expf(acc1[1][nt][r] - hk1[r]));
      }
#pragma unroll
    for (int ne = 0; ne < 5; ++ne) {
      const unsigned short* vp =
          vsT + ((size_t)bh * EE + l15 + 16 * ne) * LLEN + k0 + 4 * l4;
      s16x4 v0 = *reinterpret_cast<const s16x4*>(vp);
      s16x4 v1 = *reinterpret_cast<const s16x4*>(vp + 16);
      s16x8 vb;
#pragma unroll
      for (int i = 0; i < 4; ++i) { vb[i] = v0[i]; vb[4 + i] = v1[i]; }
#pragma unroll
      for (int MT = 0; MT < 4; ++MT)
        acc2[MT][ne] = MFMA16(pa[MT], vb, acc2[MT][ne]);
    }
  }
#pragma unroll
  for (int MT = 0; MT < 4; ++MT)
#pragma unroll
    for (int ne = 0; ne < 5; ++ne)
#pragma unroll
      for (int r = 0; r < 4; ++r) {
        int m = 16 * (4 * w + MT) + 4 * l4 + r;
        parts[(((size_t)split * 32 + bh) * MM + m) * EE + l15 + 16 * ne] = acc2[MT][ne][r];
      }
}

// ---------------------------------------------------------------------------
// reduce 16 splits -> buf1T bf16 [bh][80 e][256 m]
// ---------------------------------------------------------------------------
__global__ __launch_bounds__(256) void reduce_t(const float* __restrict__ parts,
                                                unsigned short* __restrict__ b1T) {
  int bh = blockIdx.x;   // 32
  int mc = blockIdx.y;   // 4 (64 m each)
  __shared__ float s[64 * 80];
  size_t base = ((size_t)bh * MM + mc * 64) * EE;
  for (int o = threadIdx.x; o < 64 * 80; o += 256) {
    float sum = 0.f;
#pragma unroll
    for (int sp = 0; sp < 16; ++sp)
      sum += parts[(size_t)sp * 32 * MM * EE + base + o];
    s[o] = sum;
  }
  __syncthreads();
  for (int o = threadIdx.x; o < 64 * 80; o += 256) {
    int e = o >> 6, ml = o & 63;
    b1T[((size_t)bh * EE + e) * MM + mc * 64 + ml] = f2bf(s[ml * 80 + e]);
  }
}

// ---------------------------------------------------------------------------
// F2: fused phi_q GEMM + exp + output GEMM, all in registers (no LDS).
// GEMM1 swapped: mfma(A=projB[m], B=Xq[q]) -> lane holds P[m=16mt+4l4+r][q=l15]
// GEMM3 contracts over m with the same k-perm; A-frag = bf16(exp(acc1)),
// B-frag (b1T) = two 8B loads at m-local 4l4 and 16+4l4.
// ---------------------------------------------------------------------------
__global__ __launch_bounds__(256, 3) void f2_k(
    const unsigned short* __restrict__ Xq, const unsigned short* __restrict__ projB,
    const unsigned short* __restrict__ b1T, const float* __restrict__ hqp,
    float* __restrict__ out) {
  int bh = blockIdx.x, qc = blockIdx.y;
  int b = bh >> 3, h = bh & 7;
  int w = threadIdx.x >> 6, l = threadIdx.x & 63;
  int l15 = l & 15, l4 = l >> 4;
  int qb = qc * 128 + w * 32;   // wave's 32 queries

  s16x8 xq[2][3];
#pragma unroll
  for (int qt = 0; qt < 2; ++qt)
#pragma unroll
    for (int ks = 0; ks < 3; ++ks)
      xq[qt][ks] = *reinterpret_cast<const s16x8*>(
          Xq + ((size_t)(b * LLEN + qb + 16 * qt + l15) * HH + h) * KX + 32 * ks + 8 * l4);
  float hq0 = hqp[h * NTOK + b * LLEN + qb + l15];
  float hq1 = hqp[h * NTOK + b * LLEN + qb + 16 + l15];

  f32x4 acc3[2][5] = {};
  for (int ks = 0; ks < 8; ++ks) {   // m-block of 32
    f32x4 a0 = {}, b0 = {}, a1 = {}, b1 = {};
#pragma unroll
    for (int xs = 0; xs < 3; ++xs) {
      s16x8 p0 = *reinterpret_cast<const s16x8*>(
          projB + (size_t)(l15 + 16 * (2 * ks)) * KX + 32 * xs + 8 * l4);
      s16x8 p1 = *reinterpret_cast<const s16x8*>(
          projB + (size_t)(l15 + 16 * (2 * ks + 1)) * KX + 32 * xs + 8 * l4);
      a0 = MFMA16(p0, xq[0][xs], a0);
      b0 = MFMA16(p1, xq[0][xs], b0);
      a1 = MFMA16(p0, xq[1][xs], a1);
      b1 = MFMA16(p1, xq[1][xs], b1);
    }
    s16x8 pa0, pa1;
#pragma unroll
    for (int r = 0; r < 4; ++r) {
      pa0[r]     = (short)f2bf(__expf(a0[r] - hq0));
      pa0[4 + r] = (short)f2bf(__expf(b0[r] - hq0));
      pa1[r]     = (short)f2bf(__expf(a1[r] - hq1));
      pa1[4 + r] = (short)f2bf(__expf(b1[r] - hq1));
    }
#pragma unroll
    for (int ne = 0; ne < 5; ++ne) {
      const unsigned short* vp =
          b1T + ((size_t)bh * EE + l15 + 16 * ne) * MM + 32 * ks + 4 * l4;
      s16x4 v0 = *reinterpret_cast<const s16x4*>(vp);
      s16x4 v1 = *reinterpret_cast<const s16x4*>(vp + 16);
      s16x8 vb;
#pragma unroll
      for (int i = 0; i < 4; ++i) { vb[i] = v0[i]; vb[4 + i] = v1[i]; }
      acc3[0][ne] = MFMA16(pa0, vb, acc3[0][ne]);
      acc3[1][ne] = MFMA16(pa1, vb, acc3[1][ne]);
    }
  }
#pragma unroll
  for (int qt = 0; qt < 2; ++qt) {
    float inv[4];
#pragma unroll
    for (int r = 0; r < 4; ++r) {
      float den = __shfl(acc3[qt][4][r], 16 * l4, 64);   // e=64 lives in lanes l15==0
      den = den < EPSV ? EPSV : den;
      inv[r] = 1.0f / den;
    }
#pragma unroll
    for (int ne = 0; ne < 4; ++ne)
#pragma unroll
      for (int r = 0; r < 4; ++r)
        out[((size_t)(b * LLEN + qb + 16 * qt + 4 * l4 + r) * HH + h) * 64 + l15 + 16 * ne] =
            acc3[qt][ne][r] * inv[r];
  }
}

// ---------------------------------------------------------------------------
extern "C" void kernel_launch(void* const* d_in, const int* in_sizes, int n_in,
                              void* d_out, int out_size, void* d_ws, size_t ws_size,
                              hipStream_t stream) {
  const float* qs   = (const float*)d_in[0];
  const float* ks   = (const float*)d_in[1];
  const float* vs   = (const float*)d_in[2];
  const float* qs_s = (const float*)d_in[3];
  const float* ks_s = (const float*)d_in[4];
  const float* W    = (const float*)d_in[5];
  const float* proj = (const float*)d_in[6];
  const float* a    = (const float*)d_in[7];
  float* out = (float*)d_out;

  char* ws = (char*)d_ws;
  unsigned short* projB = (unsigned short*)(ws + OFF_PROJB);
  unsigned short* Xq    = (unsigned short*)(ws + OFF_XQ);
  unsigned short* Xk    = (unsigned short*)(ws + OFF_XK);
  float*          hqp   = (float*)(ws + OFF_HQ);
  float*          hkp   = (float*)(ws + OFF_HK);
  unsigned short* vsT   = (unsigned short*)(ws + OFF_VST);
  float*          parts = (float*)(ws + OFF_PARTS);
  unsigned short* b1T   = (unsigned short*)(ws + OFF_B1T);

  prep_proj<<<1, 256, 0, stream>>>(proj, projB);
  prep_x<<<512, 256, 0, stream>>>(qs, ks, qs_s, ks_s, W, a, Xq, Xk, hqp, hkp);
  prep_vst<<<dim3(64, 32), 256, 0, stream>>>(vs, vsT);
  prep_fill<<<1024, 256, 0, stream>>>(vsT);
  f1_k<<<dim3(32, NSPLIT), 256, 0, stream>>>(Xk, projB, vsT, hkp, parts);
  reduce_t<<<dim3(32, 4), 256, 0, stream>>>(parts, b1T);
  f2_k<<<dim3(32, 32), 256, 0, stream>>>(Xq, projB, b1T, hqp, out);
}

// Round 4
// 146.081 us; speedup vs baseline: 6.8320x; 1.2812x over previous
//
#include <hip/hip_runtime.h>
#include <hip/hip_bf16.h>
#include <math.h>

// Problem dims (fixed by setup_inputs)
#define BB 4
#define LLEN 4096
#define HH 8
#define MM 256
#define KX 96          // padded x-dim: 64 qk + 8 fourier + 24 zero
#define EE 80          // padded c-dim: 64 v + 1 ones + 15 zero
#define NTOK 16384     // BB*LLEN
#define NORM 0.35355339059327373f   // 64^-0.25 (folded into projB cols 0..63)
#define NORM2 0.125f                // NORM^2
#define LN16 2.7725887222397811f    // ln(sqrt(256)) folded into h => exp includes 1/sqrt(m)
#define EPSV 1e-6f
#define TWO_PI_F 6.283185307179586f
#define NSPLIT 16
#define PX_BLOCKS 2048

typedef __attribute__((ext_vector_type(8))) short s16x8;   // 8 bf16 (4 VGPRs)
typedef __attribute__((ext_vector_type(4))) short s16x4;   // 4 bf16
typedef __attribute__((ext_vector_type(2))) short s16x2;
typedef __attribute__((ext_vector_type(4))) float f32x4;   // MFMA acc

#define MFMA16(A,B,C) __builtin_amdgcn_mfma_f32_16x16x32_bf16(A,B,C,0,0,0)

static __device__ __forceinline__ unsigned short f2bf(float f) {
  union { float f; unsigned int u; } v; v.f = f;
  unsigned int r = v.u + 0x7FFFu + ((v.u >> 16) & 1u);   // round-to-nearest-even
  return (unsigned short)(r >> 16);
}

// ---- workspace byte offsets (total ~116 MB) ----
#define OFF_PROJB 0u
#define OFF_XQ    49152u
#define OFF_XK    (OFF_XQ + 25165824u)
#define OFF_HQ    (OFF_XK + 25165824u)
#define OFF_HK    (OFF_HQ + 524288u)
#define OFF_VST   (OFF_HK + 524288u)
#define OFF_PARTS (OFF_VST + 20971520u)
#define OFF_B1T   (OFF_PARTS + 41943040u)

// ---------------------------------------------------------------------------
// projB[m][0..95] bf16: cols 0..63 = proj*NORM, 64..71 = proj, 72..95 = 0
// ---------------------------------------------------------------------------
__global__ __launch_bounds__(256) void prep_proj(const float* __restrict__ proj,
                                                 unsigned short* __restrict__ projB) {
  int m = threadIdx.x;
#pragma unroll
  for (int d = 0; d < 64; ++d) projB[m * KX + d] = f2bf(proj[m * 72 + d] * NORM);
#pragma unroll
  for (int d = 64; d < 72; ++d) projB[m * KX + d] = f2bf(proj[m * 72 + d]);
#pragma unroll
  for (int d = 72; d < 96; ++d) projB[m * KX + d] = 0;
}

// ---------------------------------------------------------------------------
// prep_x: wave-cooperative, fully coalesced. 16 lanes per (row = token*8+h,
// side). Rows 0..131071 = q-side, 131072..262143 = k-side.
// X layout: [h][token][96] bf16 (h-major for f1/f2 read locality).
// hqp/hkp[h][token] = 0.5*||x||^2 + ln(16).
// ---------------------------------------------------------------------------
__global__ __launch_bounds__(256) void prep_x(
    const float* __restrict__ qs, const float* __restrict__ ks,
    const float* __restrict__ qs_s, const float* __restrict__ ks_s,
    const float* __restrict__ W, const float* __restrict__ a,
    unsigned short* __restrict__ Xq, unsigned short* __restrict__ Xk,
    float* __restrict__ hqp, float* __restrict__ hkp) {
  const int NW_TOT = PX_BLOCKS * 4;                 // 8192 waves
  int wid = blockIdx.x * 4 + (threadIdx.x >> 6);
  int l = threadIdx.x & 63;
  int l15 = l & 15, g = l >> 4;                     // g = row within quad

  for (int qd = wid; qd < 65536; qd += NW_TOT) {    // 8 iterations
    int row = qd * 4 + g;                           // 0..262143
    bool isq = row < 131072;
    int t = isq ? row : row - 131072;               // token*8 + h
    int token = t >> 3, h = t & 7;
    const float* src = (isq ? qs : ks) + (size_t)t * 64;
    unsigned short* dst = (isq ? Xq : Xk) + ((size_t)h * NTOK + token) * KX;

    // main 64 dims: lane l15 owns floats 4*l15..4*l15+3 (wave reads 1KB contig)
    f32x4 v = *reinterpret_cast<const f32x4*>(src + 4 * l15);
    float ss = v[0] * v[0] + v[1] * v[1] + v[2] * v[2] + v[3] * v[3];
    s16x4 o;
#pragma unroll
    for (int i = 0; i < 4; ++i) o[i] = (short)f2bf(v[i]);
    *reinterpret_cast<s16x4*>(dst + 4 * l15) = o;

    // fourier dims: lanes l15<8 compute one each
    float contrib = ss * NORM2;
    if (l15 < 8) {
      float sv = (isq ? qs_s : ks_s)[token] * TWO_PI_F;
      int dim = 8 * h + l15;
      float ph = sv * W[dim & 31];
      float e = (dim < 32) ? sinf(ph) : cosf(ph);
      if (isq) e *= a[h];
      contrib += e * e;
      dst[64 + l15] = f2bf(e);
    }
    // zero pad cols 72..95: lanes l15<12 write 2 u16 each
    if (l15 < 12) {
      s16x2 z = {};
      *reinterpret_cast<s16x2*>(dst + 72 + 2 * l15) = z;
    }
    // reduce contrib over the 16-lane group
#pragma unroll
    for (int m = 1; m < 16; m <<= 1) contrib += __shfl_xor(contrib, m, 64);
    if (l15 == 0)
      (isq ? hqp : hkp)[h * NTOK + token] = 0.5f * contrib + LN16;
  }
}

// ---------------------------------------------------------------------------
// vsT[bh][e][k] bf16 for e<64 via LDS tile transpose (rows 64..79 by prep_fill)
// ---------------------------------------------------------------------------
__global__ __launch_bounds__(256) void prep_vst(const float* __restrict__ vs,
                                                unsigned short* __restrict__ vsT) {
  int kc = blockIdx.x;   // 0..63
  int bh = blockIdx.y;   // 0..31
  int b = bh >> 3, h = bh & 7;
  int t = threadIdx.x;
  __shared__ unsigned short tile[64][72];
  int k = t >> 2, seg = t & 3;
  const f32x4* src = reinterpret_cast<const f32x4*>(
      vs + (((size_t)(b * LLEN + kc * 64 + k)) * HH + h) * 64 + seg * 16);
#pragma unroll
  for (int j = 0; j < 4; ++j) {
    f32x4 v = src[j];
#pragma unroll
    for (int i = 0; i < 4; ++i) tile[k][seg * 16 + j * 4 + i] = f2bf(v[i]);
  }
  __syncthreads();
  int e = t >> 2, ksg = t & 3;
  s16x8 o0, o1;
#pragma unroll
  for (int j = 0; j < 8; ++j) o0[j] = (short)tile[ksg * 16 + j][e];
#pragma unroll
  for (int j = 0; j < 8; ++j) o1[j] = (short)tile[ksg * 16 + 8 + j][e];
  unsigned short* dst = vsT + ((size_t)bh * EE + e) * LLEN + kc * 64 + ksg * 16;
  *reinterpret_cast<s16x8*>(dst) = o0;
  *reinterpret_cast<s16x8*>(dst + 8) = o1;
}

__global__ __launch_bounds__(256) void prep_fill(unsigned short* __restrict__ vsT) {
  int t = blockIdx.x * 256 + threadIdx.x;
  int f0 = t * 8;
  int bh = f0 >> 16;
  int rem = f0 & 65535;
  int er = rem >> 12;
  int k = rem & 4095;
  unsigned short val = (er == 0) ? f2bf(1.0f) : (unsigned short)0;
  s16x8 v;
#pragma unroll
  for (int i = 0; i < 8; ++i) v[i] = (short)val;
  *reinterpret_cast<s16x8*>(vsT + ((size_t)bh * EE + 64 + er) * LLEN + k) = v;
}

// ---------------------------------------------------------------------------
// F1: fused phi_k GEMM + exp + buf1 GEMM, all in registers (no LDS).
// GEMM1: mfma(A=Xk[key], B=projB[m]) -> lane holds P[key=16kt+4l4+r][m=l15+16nt]
// k-perm for GEMM2 (contract over key): position (l4,j) <-> key_local =
// 16(j>>2)+4l4+(j&3); A-frag = bf16(exp(acc1)) in order, B-frag (vsT) = two
// 8B loads at key 4l4 and 16+4l4.
// ---------------------------------------------------------------------------
__global__ __launch_bounds__(256, 2) void f1_k(
    const unsigned short* __restrict__ Xk, const unsigned short* __restrict__ projB,
    const unsigned short* __restrict__ vsT, const float* __restrict__ hkp,
    float* __restrict__ parts) {
  int bh = blockIdx.x, split = blockIdx.y;
  int b = bh >> 3, h = bh & 7;
  int w = threadIdx.x >> 6, l = threadIdx.x & 63;
  int l15 = l & 15, l4 = l >> 4;

  s16x8 pb[4][3];   // wave's 4 m-tiles (m = l15 + 16*(4w+nt))
#pragma unroll
  for (int nt = 0; nt < 4; ++nt)
#pragma unroll
    for (int ks = 0; ks < 3; ++ks)
      pb[nt][ks] = *reinterpret_cast<const s16x8*>(
          projB + (size_t)(l15 + 16 * (4 * w + nt)) * KX + 32 * ks + 8 * l4);

  f32x4 acc2[4][5] = {};
  const float* hkb = hkp + h * NTOK + b * LLEN;
  const unsigned short* xkb = Xk + ((size_t)h * NTOK + b * LLEN) * KX;

  for (int it = 0; it < 8; ++it) {
    int k0 = split * 256 + it * 32;
    f32x4 acc1[2][4] = {};
#pragma unroll
    for (int ks = 0; ks < 3; ++ks) {
      s16x8 ak0 = *reinterpret_cast<const s16x8*>(
          xkb + (size_t)(k0 + l15) * KX + 32 * ks + 8 * l4);
      s16x8 ak1 = *reinterpret_cast<const s16x8*>(
          xkb + (size_t)(k0 + 16 + l15) * KX + 32 * ks + 8 * l4);
#pragma unroll
      for (int nt = 0; nt < 4; ++nt) {
        acc1[0][nt] = MFMA16(ak0, pb[nt][ks], acc1[0][nt]);
        acc1[1][nt] = MFMA16(ak1, pb[nt][ks], acc1[1][nt]);
      }
    }
    f32x4 hk0 = *reinterpret_cast<const f32x4*>(hkb + k0 + 4 * l4);
    f32x4 hk1 = *reinterpret_cast<const f32x4*>(hkb + k0 + 16 + 4 * l4);
    s16x8 pa[4];
#pragma unroll
    for (int nt = 0; nt < 4; ++nt)
#pragma unroll
      for (int r = 0; r < 4; ++r) {
        pa[nt][r]     = (short)f2bf(__expf(acc1[0][nt][r] - hk0[r]));
        pa[nt][4 + r] = (short)f2bf(__expf(acc1[1][nt][r] - hk1[r]));
      }
#pragma unroll
    for (int ne = 0; ne < 5; ++ne) {
      const unsigned short* vp =
          vsT + ((size_t)bh * EE + l15 + 16 * ne) * LLEN + k0 + 4 * l4;
      s16x4 v0 = *reinterpret_cast<const s16x4*>(vp);
      s16x4 v1 = *reinterpret_cast<const s16x4*>(vp + 16);
      s16x8 vb;
#pragma unroll
      for (int i = 0; i < 4; ++i) { vb[i] = v0[i]; vb[4 + i] = v1[i]; }
#pragma unroll
      for (int MT = 0; MT < 4; ++MT)
        acc2[MT][ne] = MFMA16(pa[MT], vb, acc2[MT][ne]);
    }
  }
#pragma unroll
  for (int MT = 0; MT < 4; ++MT)
#pragma unroll
    for (int ne = 0; ne < 5; ++ne)
#pragma unroll
      for (int r = 0; r < 4; ++r) {
        int m = 16 * (4 * w + MT) + 4 * l4 + r;
        parts[(((size_t)split * 32 + bh) * MM + m) * EE + l15 + 16 * ne] = acc2[MT][ne][r];
      }
}

// ---------------------------------------------------------------------------
// reduce 16 splits -> buf1T bf16 [bh][80 e][256 m]
// ---------------------------------------------------------------------------
__global__ __launch_bounds__(256) void reduce_t(const float* __restrict__ parts,
                                                unsigned short* __restrict__ b1T) {
  int bh = blockIdx.x;   // 32
  int mc = blockIdx.y;   // 4 (64 m each)
  __shared__ float s[64 * 80];
  size_t base = ((size_t)bh * MM + mc * 64) * EE;
  for (int o = threadIdx.x; o < 64 * 80; o += 256) {
    float sum = 0.f;
#pragma unroll
    for (int sp = 0; sp < 16; ++sp)
      sum += parts[(size_t)sp * 32 * MM * EE + base + o];
    s[o] = sum;
  }
  __syncthreads();
  for (int o = threadIdx.x; o < 64 * 80; o += 256) {
    int e = o >> 6, ml = o & 63;
    b1T[((size_t)bh * EE + e) * MM + mc * 64 + ml] = f2bf(s[ml * 80 + e]);
  }
}

// ---------------------------------------------------------------------------
// F2: fused phi_q GEMM + exp + output GEMM, all in registers (no LDS).
// GEMM1 swapped: mfma(A=projB[m], B=Xq[q]) -> lane holds P[m=16mt+4l4+r][q=l15]
// GEMM3 contracts over m with the same k-perm; A-frag = bf16(exp(acc1)),
// B-frag (b1T) = two 8B loads at m-local 4l4 and 16+4l4.
// ---------------------------------------------------------------------------
__global__ __launch_bounds__(256, 3) void f2_k(
    const unsigned short* __restrict__ Xq, const unsigned short* __restrict__ projB,
    const unsigned short* __restrict__ b1T, const float* __restrict__ hqp,
    float* __restrict__ out) {
  int bh = blockIdx.x, qc = blockIdx.y;
  int b = bh >> 3, h = bh & 7;
  int w = threadIdx.x >> 6, l = threadIdx.x & 63;
  int l15 = l & 15, l4 = l >> 4;
  int qb = qc * 128 + w * 32;   // wave's 32 queries
  const unsigned short* xqb = Xq + ((size_t)h * NTOK + b * LLEN) * KX;

  s16x8 xq[2][3];
#pragma unroll
  for (int qt = 0; qt < 2; ++qt)
#pragma unroll
    for (int ks = 0; ks < 3; ++ks)
      xq[qt][ks] = *reinterpret_cast<const s16x8*>(
          xqb + (size_t)(qb + 16 * qt + l15) * KX + 32 * ks + 8 * l4);
  float hq0 = hqp[h * NTOK + b * LLEN + qb + l15];
  float hq1 = hqp[h * NTOK + b * LLEN + qb + 16 + l15];

  f32x4 acc3[2][5] = {};
  for (int ks = 0; ks < 8; ++ks) {   // m-block of 32
    f32x4 a0 = {}, b0 = {}, a1 = {}, b1 = {};
#pragma unroll
    for (int xs = 0; xs < 3; ++xs) {
      s16x8 p0 = *reinterpret_cast<const s16x8*>(
          projB + (size_t)(l15 + 16 * (2 * ks)) * KX + 32 * xs + 8 * l4);
      s16x8 p1 = *reinterpret_cast<const s16x8*>(
          projB + (size_t)(l15 + 16 * (2 * ks + 1)) * KX + 32 * xs + 8 * l4);
      a0 = MFMA16(p0, xq[0][xs], a0);
      b0 = MFMA16(p1, xq[0][xs], b0);
      a1 = MFMA16(p0, xq[1][xs], a1);
      b1 = MFMA16(p1, xq[1][xs], b1);
    }
    s16x8 pa0, pa1;
#pragma unroll
    for (int r = 0; r < 4; ++r) {
      pa0[r]     = (short)f2bf(__expf(a0[r] - hq0));
      pa0[4 + r] = (short)f2bf(__expf(b0[r] - hq0));
      pa1[r]     = (short)f2bf(__expf(a1[r] - hq1));
      pa1[4 + r] = (short)f2bf(__expf(b1[r] - hq1));
    }
#pragma unroll
    for (int ne = 0; ne < 5; ++ne) {
      const unsigned short* vp =
          b1T + ((size_t)bh * EE + l15 + 16 * ne) * MM + 32 * ks + 4 * l4;
      s16x4 v0 = *reinterpret_cast<const s16x4*>(vp);
      s16x4 v1 = *reinterpret_cast<const s16x4*>(vp + 16);
      s16x8 vb;
#pragma unroll
      for (int i = 0; i < 4; ++i) { vb[i] = v0[i]; vb[4 + i] = v1[i]; }
      acc3[0][ne] = MFMA16(pa0, vb, acc3[0][ne]);
      acc3[1][ne] = MFMA16(pa1, vb, acc3[1][ne]);
    }
  }
#pragma unroll
  for (int qt = 0; qt < 2; ++qt) {
    float inv[4];
#pragma unroll
    for (int r = 0; r < 4; ++r) {
      float den = __shfl(acc3[qt][4][r], 16 * l4, 64);   // e=64 lives in lanes l15==0
      den = den < EPSV ? EPSV : den;
      inv[r] = 1.0f / den;
    }
#pragma unroll
    for (int ne = 0; ne < 4; ++ne)
#pragma unroll
      for (int r = 0; r < 4; ++r)
        out[((size_t)(b * LLEN + qb + 16 * qt + 4 * l4 + r) * HH + h) * 64 + l15 + 16 * ne] =
            acc3[qt][ne][r] * inv[r];
  }
}

// ---------------------------------------------------------------------------
extern "C" void kernel_launch(void* const* d_in, const int* in_sizes, int n_in,
                              void* d_out, int out_size, void* d_ws, size_t ws_size,
                              hipStream_t stream) {
  const float* qs   = (const float*)d_in[0];
  const float* ks   = (const float*)d_in[1];
  const float* vs   = (const float*)d_in[2];
  const float* qs_s = (const float*)d_in[3];
  const float* ks_s = (const float*)d_in[4];
  const float* W    = (const float*)d_in[5];
  const float* proj = (const float*)d_in[6];
  const float* a    = (const float*)d_in[7];
  float* out = (float*)d_out;

  char* ws = (char*)d_ws;
  unsigned short* projB = (unsigned short*)(ws + OFF_PROJB);
  unsigned short* Xq    = (unsigned short*)(ws + OFF_XQ);
  unsigned short* Xk    = (unsigned short*)(ws + OFF_XK);
  float*          hqp   = (float*)(ws + OFF_HQ);
  float*          hkp   = (float*)(ws + OFF_HK);
  unsigned short* vsT   = (unsigned short*)(ws + OFF_VST);
  float*          parts = (float*)(ws + OFF_PARTS);
  unsigned short* b1T   = (unsigned short*)(ws + OFF_B1T);

  prep_proj<<<1, 256, 0, stream>>>(proj, projB);
  prep_x<<<PX_BLOCKS, 256, 0, stream>>>(qs, ks, qs_s, ks_s, W, a, Xq, Xk, hqp, hkp);
  prep_vst<<<dim3(64, 32), 256, 0, stream>>>(vs, vsT);
  prep_fill<<<1024, 256, 0, stream>>>(vsT);
  f1_k<<<dim3(32, NSPLIT), 256, 0, stream>>>(Xk, projB, vsT, hkp, parts);
  reduce_t<<<dim3(32, 4), 256, 0, stream>>>(parts, b1T);
  f2_k<<<dim3(32, 32), 256, 0, stream>>>(Xq, projB, b1T, hqp, out);
}